// Round 18
// baseline (336.515 us; speedup 1.0000x reference)
//
#include <hip/hip_runtime.h>
#include <hip/hip_cooperative_groups.h>
#include <math.h>

namespace cg = cooperative_groups;

#define B_ 4
#define C_ 128
#define CI_ 64
#define H_ 96
#define W_ 96
#define HW_ (H_*W_)      // 9216
#define NP_ 2304         // 48*48
#define GROUPS_ 32
#define EPS_ 1e-5f
#define KVT_ 32          // KV tile rows
#define NT_ (NP_/KVT_)   // 72 tiles
#define NBLK_ 288        // 32-px blocks (attn grid per b; gpart stride)

typedef _Float16 f16x8 __attribute__((ext_vector_type(8)));
typedef _Float16 f16x2 __attribute__((ext_vector_type(2)));
typedef __attribute__((ext_vector_type(4))) float f32x4;

__device__ inline f32x4 mfma16h(f16x8 a, f16x8 b, f32x4 c) {
    return __builtin_amdgcn_mfma_f32_16x16x32_f16(a, b, c, 0, 0, 0);
}
__device__ inline float h2f(unsigned short s) {
    return (float)__builtin_bit_cast(_Float16, s);
}
__device__ inline unsigned pk_f16(float a, float b) {     // pack 2 f32 -> 2 f16 (RTZ)
    return __builtin_bit_cast(unsigned, __builtin_amdgcn_cvt_pkrtz(a, b));
}
__device__ inline f16x8 pk8(float v0, float v1, float v2, float v3,
                            float v4, float v5, float v6, float v7) {
    uint4 u = { pk_f16(v0, v1), pk_f16(v2, v3), pk_f16(v4, v5), pk_f16(v6, v7) };
    return __builtin_bit_cast(f16x8, u);
}
__device__ inline unsigned short hmax4(unsigned short a, unsigned short b,
                                       unsigned short c, unsigned short d) {
    unsigned short m = (h2f(a) >= h2f(b)) ? a : b;
    unsigned short n = (h2f(c) >= h2f(d)) ? c : d;
    return (h2f(m) >= h2f(n)) ? m : n;
}
// global -> LDS direct DMA, 16B/lane. LDS dest = wave-uniform base + lane*16.
__device__ inline void gload_lds16(const void* g, void* l) {
    __builtin_amdgcn_global_load_lds(
        (const __attribute__((address_space(1))) void*)reinterpret_cast<uintptr_t>(g),
        (__attribute__((address_space(3))) void*)(unsigned)reinterpret_cast<uintptr_t>(l),
        16, 0, 0);
}

// ---------------------------------------------------------------------------
// Kernel 0: cast the 4 weight matrices to fp16 (Whall[32768]).
// ---------------------------------------------------------------------------
__global__ __launch_bounds__(256) void wprep_kernel(
    const float* __restrict__ w_theta, const float* __restrict__ w_phi,
    const float* __restrict__ w_g,     const float* __restrict__ w_W,
    unsigned short* __restrict__ Whall)
{
    const int idx = blockIdx.x * 256 + threadIdx.x;   // 0..32767
    float v;
    if      (idx <  8192) v = w_theta[idx];
    else if (idx < 16384) v = w_phi[idx - 8192];
    else if (idx < 24576) v = w_g[idx - 16384];
    else                  v = w_W[idx - 24576];
    Whall[idx] = __builtin_bit_cast(unsigned short, (_Float16)v);
}

// ---------------------------------------------------------------------------
// Kernel 1: fused projections + 2x2 maxpool (R16, unchanged).
// ---------------------------------------------------------------------------
__global__ __launch_bounds__(128) void proj_kernel(
    const float* __restrict__ x, const unsigned short* __restrict__ Whall,
    const float* __restrict__ b_theta, const float* __restrict__ b_phi,
    const float* __restrict__ b_g,
    unsigned short* __restrict__ Qo, unsigned short* __restrict__ Ko,
    unsigned short* __restrict__ Vt)
{
    __shared__ __align__(16) unsigned short pb[2][16 * 72];   // per-wave row

    const int t    = threadIdx.x;
    const int wv   = t >> 6;
    const int lane = t & 63;
    const int lr   = lane & 15;
    const int lg   = lane >> 4;
    const int b    = blockIdx.y;
    const int h0   = (blockIdx.x / 6) * 2;
    const int w0   = (blockIdx.x % 6) * 16;
    const int nb   = (h0 + wv) * W_ + w0;          // wave's 16-px base
    const int m0   = (h0 >> 1) * 48 + (w0 >> 1);   // pooled base (8 m-values)

    const float* xb = x + (size_t)b * C_ * HW_ + nb + lr;
    f16x8 xa[4];
    #pragma unroll
    for (int u = 0; u < 4; ++u) {
        const float* p = xb + (size_t)(u * 32 + lg * 8) * HW_;
        xa[u] = pk8(p[0], p[(size_t)HW_], p[2 * (size_t)HW_], p[3 * (size_t)HW_],
                    p[4 * (size_t)HW_], p[5 * (size_t)HW_], p[6 * (size_t)HW_],
                    p[7 * (size_t)HW_]);
    }

    #pragma unroll
    for (int mat = 0; mat < 3; ++mat) {
        const unsigned short* Whp = Whall + mat * 8192;
        const float* bsel = (mat == 0) ? b_theta : (mat == 1) ? b_phi : b_g;

        f32x4 D[4];
        #pragma unroll
        for (int ct = 0; ct < 4; ++ct) D[ct] = (f32x4){0.f, 0.f, 0.f, 0.f};
        #pragma unroll
        for (int u = 0; u < 4; ++u)
            #pragma unroll
            for (int ct = 0; ct < 4; ++ct) {
                f16x8 wb = *(const f16x8*)&Whp[(ct * 16 + lr) * 128 + u * 32 + lg * 8];
                D[ct] = mfma16h(xa[u], wb, D[ct]);
            }

        #pragma unroll
        for (int ct = 0; ct < 4; ++ct) {
            const float bi = bsel[ct * 16 + lr];
            #pragma unroll
            for (int r2 = 0; r2 < 4; ++r2)
                pb[wv][(4 * lg + r2) * 72 + ct * 16 + lr] =
                    __builtin_bit_cast(unsigned short, (_Float16)(D[ct][r2] + bi));
        }

        if (mat == 0) {
            const int px = lane >> 2, ch = lane & 3;
            f16x8 y0 = *(const f16x8*)&pb[wv][px * 72 + ch * 16];
            f16x8 y1 = *(const f16x8*)&pb[wv][px * 72 + ch * 16 + 8];
            unsigned short* op = Qo + ((size_t)b * HW_ + nb + px) * CI_ + ch * 16;
            *(f16x8*)op       = y0;
            *(f16x8*)(op + 8) = y1;
        } else if (mat == 1) {
            __syncthreads();
            const int w = t >> 4, ci0 = (t & 15) * 4;
            unsigned short r[4];
            #pragma unroll
            for (int j = 0; j < 4; ++j) {
                const int ci = ci0 + j;
                r[j] = hmax4(pb[0][(2 * w) * 72 + ci], pb[0][(2 * w + 1) * 72 + ci],
                             pb[1][(2 * w) * 72 + ci], pb[1][(2 * w + 1) * 72 + ci]);
            }
            *(ushort4*)&Ko[((size_t)b * NP_ + m0 + w) * CI_ + ci0] =
                (ushort4){r[0], r[1], r[2], r[3]};
            __syncthreads();
        } else {
            __syncthreads();
            const int ci = t >> 1, pr = t & 1;
            #pragma unroll
            for (int j = 0; j < 4; ++j) {
                const int w = pr * 4 + j;
                unsigned short v = hmax4(
                    pb[0][(2 * w) * 72 + ci], pb[0][(2 * w + 1) * 72 + ci],
                    pb[1][(2 * w) * 72 + ci], pb[1][(2 * w + 1) * 72 + ci]);
                const int m  = m0 + w;
                const int ms = (m & ~31)
                             | (8 * ((m >> 2) & 3) + 4 * ((m >> 4) & 1) + (m & 3));
                Vt[((size_t)b * CI_ + ci) * NP_ + ms] = v;
            }
        }
    }
}

// ---------------------------------------------------------------------------
// Kernel 3 (COOPERATIVE): flash attention + conv-back + GN + residual.
// Main loop = R12 structure byte-identical. Epilogue: Y->LDS bounce, conv-back
// MFMA into REGISTERS (Z never hits global), GN partials -> gpart,
// grid.sync(), per-block stats reduce (L2-hot gpart), normalize in-reg Z,
// LDS-transpose to zb[128][32] for full-128B-row coalesced x/out streaming.
// ---------------------------------------------------------------------------
__global__ __launch_bounds__(128, 3) void attn_kernel(
    const unsigned short* __restrict__ Qg, const unsigned short* __restrict__ Kg,
    const unsigned short* __restrict__ Vt, const unsigned short* __restrict__ wWh,
    const float* __restrict__ bW, const float* __restrict__ xg,
    const float* __restrict__ gnw, const float* __restrict__ gnb,
    float* __restrict__ gpart, float* __restrict__ out)
{
    __shared__ __align__(16) unsigned char SMEM[16384];  // K/V staging, later zb
    __shared__ float sred[128];
    __shared__ float mstat[32][2];
    __shared__ float gwb[128][2];
#define KLDS(BUF) (SMEM + (BUF) * 4096)
#define VLDS(BUF) (SMEM + 8192 + (BUF) * 4096)

    const int t    = threadIdx.x;
    const int wv   = t >> 6;
    const int lane = t & 63;
    const int lr   = lane & 15;
    const int lg   = lane >> 4;
    const int b    = blockIdx.y;
    const int q0   = blockIdx.x * 32 + wv * 16;

    gwb[t][0] = gnw[t & 127];                        // stage GN affine (L2-hot)
    gwb[t][1] = gnb[t & 127];

    const int krow = lane >> 3;                       // K staging: 8 rows/load
    const int kchk = (lane & 7) ^ krow;               // inverse-swizzled chunk
    const int vrow = lane >> 2;                       // V staging: 16 rows/load
    const int vchk = (lane & 3) ^ (vrow & 3);

    const unsigned short* Kb = Kg + (size_t)b * NP_ * CI_;
    const unsigned short* Vb = Vt + (size_t)b * CI_ * NP_;

    f16x8 qf[2];
    #pragma unroll
    for (int u = 0; u < 2; ++u)
        qf[u] = *(const f16x8*)(Qg + ((size_t)b * HW_ + q0 + lr) * CI_ + u * 32 + lg * 8);

    f32x4 o_acc[4];
    #pragma unroll
    for (int dt = 0; dt < 4; ++dt) o_acc[dt] = (f32x4){0.f, 0.f, 0.f, 0.f};
    float mrun = -1e30f, lrun = 0.f;

#define STAGE(BUF, TT)                                                          \
    {                                                                           \
        const int kv0_ = (TT) * KVT_;                                           \
        if (wv == 0) {                                                          \
            _Pragma("unroll")                                                   \
            for (int i = 0; i < 4; ++i)                                         \
                gload_lds16(Kb + (size_t)(kv0_ + 8 * i + krow) * CI_ + kchk * 8,\
                            KLDS(BUF) + i * 1024);                              \
        } else {                                                                \
            _Pragma("unroll")                                                   \
            for (int i = 0; i < 4; ++i)                                         \
                gload_lds16(Vb + (size_t)(16 * i + vrow) * NP_ + kv0_ + vchk * 8,\
                            VLDS(BUF) + i * 1024);                              \
        }                                                                       \
    }

#define COMPUTE(BUF)                                                            \
    {                                                                           \
        f16x8 kf[2][2];                                                         \
        _Pragma("unroll")                                                       \
        for (int u = 0; u < 2; ++u)                                             \
            _Pragma("unroll")                                                   \
            for (int k4 = 0; k4 < 2; ++k4)                                      \
                kf[u][k4] = *(const f16x8*)(KLDS(BUF) + (k4 * 16 + lr) * 128    \
                                + (((4 * u + lg) ^ (lr & 7)) << 4));            \
        f32x4 s[2];                                                             \
        s[0] = (f32x4){0.f, 0.f, 0.f, 0.f};                                     \
        s[1] = (f32x4){0.f, 0.f, 0.f, 0.f};                                     \
        __builtin_amdgcn_s_setprio(1);                                          \
        _Pragma("unroll")                                                       \
        for (int u = 0; u < 2; ++u) {                                           \
            s[0] = mfma16h(kf[u][0], qf[u], s[0]);                              \
            s[1] = mfma16h(kf[u][1], qf[u], s[1]);                              \
        }                                                                       \
        __builtin_amdgcn_s_setprio(0);                                          \
        float tmax = fmaxf(fmaxf(fmaxf(s[0][0], s[0][1]),                       \
                                 fmaxf(s[0][2], s[0][3])),                      \
                           fmaxf(fmaxf(s[1][0], s[1][1]),                       \
                                 fmaxf(s[1][2], s[1][3])));                     \
        if (!__all(tmax <= mrun + 8.0f)) {                                      \
            tmax = fmaxf(tmax, __shfl_xor(tmax, 16));                           \
            tmax = fmaxf(tmax, __shfl_xor(tmax, 32));                           \
            const float mnew = fmaxf(mrun, tmax);                               \
            const float sc = __expf(mrun - mnew);                               \
            lrun *= sc;                                                         \
            _Pragma("unroll")                                                   \
            for (int r2 = 0; r2 < 4; ++r2) {                                    \
                const float scb = __shfl(sc, 4 * lg + r2);                      \
                _Pragma("unroll")                                               \
                for (int dt = 0; dt < 4; ++dt) o_acc[dt][r2] *= scb;            \
            }                                                                   \
            mrun = mnew;                                                        \
        }                                                                       \
        const float e00 = __expf(s[0][0] - mrun);                               \
        const float e01 = __expf(s[0][1] - mrun);                               \
        const float e02 = __expf(s[0][2] - mrun);                               \
        const float e03 = __expf(s[0][3] - mrun);                               \
        const float e10 = __expf(s[1][0] - mrun);                               \
        const float e11 = __expf(s[1][1] - mrun);                               \
        const float e12 = __expf(s[1][2] - mrun);                               \
        const float e13 = __expf(s[1][3] - mrun);                               \
        lrun += ((e00 + e01) + (e02 + e03)) + ((e10 + e11) + (e12 + e13));      \
        f16x8 pf = pk8(e00, e01, e02, e03, e10, e11, e12, e13);                 \
        __builtin_amdgcn_s_setprio(1);                                          \
        _Pragma("unroll")                                                       \
        for (int dt = 0; dt < 4; ++dt) {                                        \
            const int vrow_ = dt * 16 + lr;                                     \
            f16x8 vf = *(const f16x8*)(VLDS(BUF) + vrow_ * 64                   \
                            + (((lg ^ (lr & 3))) << 4));                        \
            o_acc[dt] = mfma16h(pf, vf, o_acc[dt]);                             \
        }                                                                       \
        __builtin_amdgcn_s_setprio(0);                                          \
    }

    STAGE(0, 0);
    STAGE(1, 1);

    for (int it = 0; it < NT_ / 2; ++it) {
        const int t0 = 2 * it;
        asm volatile("s_waitcnt vmcnt(4)" ::: "memory");
        __builtin_amdgcn_s_barrier();
        COMPUTE(0);
        __builtin_amdgcn_s_barrier();
        if (t0 + 2 < NT_) STAGE(0, t0 + 2);
        if (it == NT_ / 2 - 1) {
            asm volatile("s_waitcnt vmcnt(0)" ::: "memory");
        } else {
            asm volatile("s_waitcnt vmcnt(4)" ::: "memory");
        }
        __builtin_amdgcn_s_barrier();
        COMPUTE(1);
        __builtin_amdgcn_s_barrier();
        if (t0 + 3 < NT_) STAGE(1, t0 + 3);
    }

    // ---- Y finalize into LDS bounce (conv2 fragment layout) ----------------
    float lt = lrun;
    lt += __shfl_xor(lt, 16);
    lt += __shfl_xor(lt, 32);
    unsigned short* yb = (unsigned short*)(SMEM + wv * 4096);   // [16][72]
    #pragma unroll
    for (int r2 = 0; r2 < 4; ++r2) {
        const float inv = 1.0f / __shfl(lt, 4 * lg + r2);
        #pragma unroll
        for (int dt = 0; dt < 4; ++dt)
            yb[(4 * lg + r2) * 72 + dt * 16 + lr] =
                __builtin_bit_cast(unsigned short, (_Float16)(o_acc[dt][r2] * inv));
    }

    // ---- fused conv-back into REGISTERS + GN partials ----------------------
    float* wpart = (float*)(SMEM + 8192);                 // [2][32][2] floats
    f16x8 ya[2];
    #pragma unroll
    for (int u = 0; u < 2; ++u)
        ya[u] = *(const f16x8*)&yb[lr * 72 + u * 32 + lg * 8];

    float zreg[8][4];
    #pragma unroll
    for (int ot = 0; ot < 8; ++ot) {
        f32x4 D = (f32x4){0.f, 0.f, 0.f, 0.f};
        #pragma unroll
        for (int u = 0; u < 2; ++u) {
            f16x8 wa = *(const f16x8*)&wWh[(ot * 16 + lr) * CI_ + u * 32 + lg * 8];
            D = mfma16h(wa, ya[u], D);
        }
        float zs = 0.f, zq = 0.f;
        #pragma unroll
        for (int r2 = 0; r2 < 4; ++r2) {
            const int o = ot * 16 + 4 * lg + r2;
            const float z = D[r2] + bW[o];
            zreg[ot][r2] = z;
            zs += z;
            zq += z * z;
        }
        zs += __shfl_xor(zs, 1);  zq += __shfl_xor(zq, 1);
        zs += __shfl_xor(zs, 2);  zq += __shfl_xor(zq, 2);
        zs += __shfl_xor(zs, 4);  zq += __shfl_xor(zq, 4);
        zs += __shfl_xor(zs, 8);  zq += __shfl_xor(zq, 8);
        if (lr == 0) {
            wpart[(wv * 32 + ot * 4 + lg) * 2 + 0] = zs;
            wpart[(wv * 32 + ot * 4 + lg) * 2 + 1] = zq;
        }
    }
    __syncthreads();
    if (t < 64) {
        const int g = t >> 1, w = t & 1;
        const float v = wpart[g * 2 + w] + wpart[(32 + g) * 2 + w];
        gpart[(((size_t)b * NBLK_ + blockIdx.x) * 32 + g) * 2 + w] = v;
    }

    // ---- grid-wide sync; then per-block GN stats from L2-hot gpart ---------
    __threadfence();
    cg::this_grid().sync();

    {
        const int gw = t & 63;                       // (g = gw>>1, w = gw&1)
        const float* gp = gpart + (size_t)b * NBLK_ * 64 + gw;
        float acc = 0.f;
        for (int j = (t >> 6); j < NBLK_; j += 2)
            acc += gp[(size_t)j * 64];
        sred[t] = acc;
    }
    __syncthreads();
    if (t < 64) ((float*)mstat)[t] = sred[t] + sred[t + 64];
    __syncthreads();
    if (t < 32) {
        const float invn = 1.0f / (4 * HW_);
        const float m = mstat[t][0] * invn;
        const float v = mstat[t][1] * invn - m * m;
        mstat[t][0] = m;
        mstat[t][1] = rsqrtf(v + EPS_);
    }
    __syncthreads();

    // ---- normalize in-reg Z -> zb[128 o][32 px] (overlays SMEM) ------------
    float* zb = (float*)SMEM;
    #pragma unroll
    for (int ot = 0; ot < 8; ++ot)
        #pragma unroll
        for (int r2 = 0; r2 < 4; ++r2) {
            const int o = ot * 16 + 4 * lg + r2;
            const int g = o >> 2;
            const float sc = mstat[g][1] * gwb[o][0];
            const float sh = gwb[o][1] - mstat[g][0] * sc;
            zb[o * 32 + wv * 16 + lr] = zreg[ot][r2] * sc + sh;
        }
    __syncthreads();

    // ---- residual + coalesced out (128B rows: 32 px per channel row) -------
    {
        const size_t rb = (size_t)b * C_ * HW_ + blockIdx.x * 32;
        const float* xr = xg + rb;
        float* orow = out + rb;
        #pragma unroll
        for (int i = 0; i < 32; ++i) {
            const int flat = i * 128 + t;
            const int o  = flat >> 5;
            const int px = flat & 31;
            orow[(size_t)o * HW_ + px] = zb[flat] + xr[(size_t)o * HW_ + px];
        }
    }
#undef STAGE
#undef COMPUTE
#undef KLDS
#undef VLDS
}

// ---------------------------------------------------------------------------
extern "C" void kernel_launch(void* const* d_in, const int* in_sizes, int n_in,
                              void* d_out, int out_size, void* d_ws, size_t ws_size,
                              hipStream_t stream)
{
    const float* x       = (const float*)d_in[0];
    const float* w_theta = (const float*)d_in[1];
    const float* b_theta = (const float*)d_in[2];
    const float* w_phi   = (const float*)d_in[3];
    const float* b_phi   = (const float*)d_in[4];
    const float* w_g     = (const float*)d_in[5];
    const float* b_g     = (const float*)d_in[6];
    const float* w_W     = (const float*)d_in[7];
    const float* b_W     = (const float*)d_in[8];
    const float* gn_w    = (const float*)d_in[9];
    const float* gn_b    = (const float*)d_in[10];
    float* out = (float*)d_out;
    char* wsb  = (char*)d_ws;

    // workspace layout (bytes)
    unsigned short* Q    = (unsigned short*)(wsb);             //  4,718,592
    unsigned short* K    = (unsigned short*)(wsb +  4718592);  //  1,179,648
    unsigned short* Vt   = (unsigned short*)(wsb +  5898240);  //  1,179,648
    float* gpart         = (float*)(wsb + 11796480);           //    294,912
    unsigned short* Whall= (unsigned short*)(wsb + 35390464);  //     65,536
    const unsigned short* wWh = Whall + 24576;

    wprep_kernel<<<128, 256, 0, stream>>>(w_theta, w_phi, w_g, w_W, Whall);
    proj_kernel <<<dim3(288, B_), 128, 0, stream>>>(
        x, Whall, b_theta, b_phi, b_g, Q, K, Vt);

    void* args[] = { (void*)&Q, (void*)&K, (void*)&Vt, (void*)&wWh,
                     (void*)&b_W, (void*)&x, (void*)&gn_w, (void*)&gn_b,
                     (void*)&gpart, (void*)&out };
    hipLaunchCooperativeKernel((void*)attn_kernel, dim3(HW_ / 32, B_),
                               dim3(128), args, 0, stream);
}

// Round 20
// 96.653 us; speedup vs baseline: 3.4817x; 3.4817x over previous
//
#include <hip/hip_runtime.h>
#include <math.h>

#define B_ 4
#define C_ 128
#define CI_ 64
#define H_ 96
#define W_ 96
#define HW_ (H_*W_)      // 9216
#define NP_ 2304         // 48*48
#define GROUPS_ 32
#define EPS_ 1e-5f
#define KVT_ 32          // KV tile rows
#define NT_ (NP_/KVT_)   // 72 tiles
#define NBLK_ 288        // 32-px blocks (attn grid per b; gpart stride)

typedef _Float16 f16x8 __attribute__((ext_vector_type(8)));
typedef _Float16 f16x2 __attribute__((ext_vector_type(2)));
typedef __attribute__((ext_vector_type(4))) float f32x4;

__device__ inline f32x4 mfma16h(f16x8 a, f16x8 b, f32x4 c) {
    return __builtin_amdgcn_mfma_f32_16x16x32_f16(a, b, c, 0, 0, 0);
}
__device__ inline float h2f(unsigned short s) {
    return (float)__builtin_bit_cast(_Float16, s);
}
__device__ inline unsigned pk_f16(float a, float b) {     // pack 2 f32 -> 2 f16 (RTZ)
    return __builtin_bit_cast(unsigned, __builtin_amdgcn_cvt_pkrtz(a, b));
}
__device__ inline f16x8 pk8(float v0, float v1, float v2, float v3,
                            float v4, float v5, float v6, float v7) {
    uint4 u = { pk_f16(v0, v1), pk_f16(v2, v3), pk_f16(v4, v5), pk_f16(v6, v7) };
    return __builtin_bit_cast(f16x8, u);
}
__device__ inline unsigned short hmax4(unsigned short a, unsigned short b,
                                       unsigned short c, unsigned short d) {
    unsigned short m = (h2f(a) >= h2f(b)) ? a : b;
    unsigned short n = (h2f(c) >= h2f(d)) ? c : d;
    return (h2f(m) >= h2f(n)) ? m : n;
}
// global -> LDS direct DMA, 16B/lane. LDS dest = wave-uniform base + lane*16.
__device__ inline void gload_lds16(const void* g, void* l) {
    __builtin_amdgcn_global_load_lds(
        (const __attribute__((address_space(1))) void*)reinterpret_cast<uintptr_t>(g),
        (__attribute__((address_space(3))) void*)(unsigned)reinterpret_cast<uintptr_t>(l),
        16, 0, 0);
}

// ---------------------------------------------------------------------------
// Kernel 0: cast the 4 weight matrices to fp16 (Whall[32768]).
// ---------------------------------------------------------------------------
__global__ __launch_bounds__(256) void wprep_kernel(
    const float* __restrict__ w_theta, const float* __restrict__ w_phi,
    const float* __restrict__ w_g,     const float* __restrict__ w_W,
    unsigned short* __restrict__ Whall)
{
    const int idx = blockIdx.x * 256 + threadIdx.x;   // 0..32767
    float v;
    if      (idx <  8192) v = w_theta[idx];
    else if (idx < 16384) v = w_phi[idx - 8192];
    else if (idx < 24576) v = w_g[idx - 16384];
    else                  v = w_W[idx - 24576];
    Whall[idx] = __builtin_bit_cast(unsigned short, (_Float16)v);
}

// ---------------------------------------------------------------------------
// Kernel 1: fused projections + 2x2 maxpool (R16, unchanged).
// ---------------------------------------------------------------------------
__global__ __launch_bounds__(128) void proj_kernel(
    const float* __restrict__ x, const unsigned short* __restrict__ Whall,
    const float* __restrict__ b_theta, const float* __restrict__ b_phi,
    const float* __restrict__ b_g,
    unsigned short* __restrict__ Qo, unsigned short* __restrict__ Ko,
    unsigned short* __restrict__ Vt)
{
    __shared__ __align__(16) unsigned short pb[2][16 * 72];   // per-wave row

    const int t    = threadIdx.x;
    const int wv   = t >> 6;
    const int lane = t & 63;
    const int lr   = lane & 15;
    const int lg   = lane >> 4;
    const int b    = blockIdx.y;
    const int h0   = (blockIdx.x / 6) * 2;
    const int w0   = (blockIdx.x % 6) * 16;
    const int nb   = (h0 + wv) * W_ + w0;          // wave's 16-px base
    const int m0   = (h0 >> 1) * 48 + (w0 >> 1);   // pooled base (8 m-values)

    const float* xb = x + (size_t)b * C_ * HW_ + nb + lr;
    f16x8 xa[4];
    #pragma unroll
    for (int u = 0; u < 4; ++u) {
        const float* p = xb + (size_t)(u * 32 + lg * 8) * HW_;
        xa[u] = pk8(p[0], p[(size_t)HW_], p[2 * (size_t)HW_], p[3 * (size_t)HW_],
                    p[4 * (size_t)HW_], p[5 * (size_t)HW_], p[6 * (size_t)HW_],
                    p[7 * (size_t)HW_]);
    }

    #pragma unroll
    for (int mat = 0; mat < 3; ++mat) {
        const unsigned short* Whp = Whall + mat * 8192;
        const float* bsel = (mat == 0) ? b_theta : (mat == 1) ? b_phi : b_g;

        f32x4 D[4];
        #pragma unroll
        for (int ct = 0; ct < 4; ++ct) D[ct] = (f32x4){0.f, 0.f, 0.f, 0.f};
        #pragma unroll
        for (int u = 0; u < 4; ++u)
            #pragma unroll
            for (int ct = 0; ct < 4; ++ct) {
                f16x8 wb = *(const f16x8*)&Whp[(ct * 16 + lr) * 128 + u * 32 + lg * 8];
                D[ct] = mfma16h(xa[u], wb, D[ct]);
            }

        #pragma unroll
        for (int ct = 0; ct < 4; ++ct) {
            const float bi = bsel[ct * 16 + lr];
            #pragma unroll
            for (int r2 = 0; r2 < 4; ++r2)
                pb[wv][(4 * lg + r2) * 72 + ct * 16 + lr] =
                    __builtin_bit_cast(unsigned short, (_Float16)(D[ct][r2] + bi));
        }

        if (mat == 0) {
            const int px = lane >> 2, ch = lane & 3;
            f16x8 y0 = *(const f16x8*)&pb[wv][px * 72 + ch * 16];
            f16x8 y1 = *(const f16x8*)&pb[wv][px * 72 + ch * 16 + 8];
            unsigned short* op = Qo + ((size_t)b * HW_ + nb + px) * CI_ + ch * 16;
            *(f16x8*)op       = y0;
            *(f16x8*)(op + 8) = y1;
        } else if (mat == 1) {
            __syncthreads();
            const int w = t >> 4, ci0 = (t & 15) * 4;
            unsigned short r[4];
            #pragma unroll
            for (int j = 0; j < 4; ++j) {
                const int ci = ci0 + j;
                r[j] = hmax4(pb[0][(2 * w) * 72 + ci], pb[0][(2 * w + 1) * 72 + ci],
                             pb[1][(2 * w) * 72 + ci], pb[1][(2 * w + 1) * 72 + ci]);
            }
            *(ushort4*)&Ko[((size_t)b * NP_ + m0 + w) * CI_ + ci0] =
                (ushort4){r[0], r[1], r[2], r[3]};
            __syncthreads();
        } else {
            __syncthreads();
            const int ci = t >> 1, pr = t & 1;
            #pragma unroll
            for (int j = 0; j < 4; ++j) {
                const int w = pr * 4 + j;
                unsigned short v = hmax4(
                    pb[0][(2 * w) * 72 + ci], pb[0][(2 * w + 1) * 72 + ci],
                    pb[1][(2 * w) * 72 + ci], pb[1][(2 * w + 1) * 72 + ci]);
                const int m  = m0 + w;
                const int ms = (m & ~31)
                             | (8 * ((m >> 2) & 3) + 4 * ((m >> 4) & 1) + (m & 3));
                Vt[((size_t)b * CI_ + ci) * NP_ + ms] = v;
            }
        }
    }
}

// ---------------------------------------------------------------------------
// Kernel 3: fp16 MFMA flash attention + FUSED conv-back (wW·Y + bias -> Z)
// + GN partial sums (R17 verified, 63.7 us).
// ---------------------------------------------------------------------------
__global__ __launch_bounds__(128) void attn_kernel(
    const unsigned short* __restrict__ Qg, const unsigned short* __restrict__ Kg,
    const unsigned short* __restrict__ Vt, const unsigned short* __restrict__ wWh,
    const float* __restrict__ bW, unsigned short* __restrict__ Zh,
    float* __restrict__ gpart)
{
    __shared__ unsigned char Klds[2][4096];   // [buf][32 k-rows x 128B]
    __shared__ unsigned char Vlds[2][4096];   // [buf][64 d-rows x  64B]

    const int t    = threadIdx.x;
    const int wv   = t >> 6;
    const int lane = t & 63;
    const int lr   = lane & 15;
    const int lg   = lane >> 4;
    const int b    = blockIdx.y;
    const int q0   = blockIdx.x * 32 + wv * 16;

    const int krow = lane >> 3;                       // K staging: 8 rows/load
    const int kchk = (lane & 7) ^ krow;               // inverse-swizzled chunk
    const int vrow = lane >> 2;                       // V staging: 16 rows/load
    const int vchk = (lane & 3) ^ (vrow & 3);

    const unsigned short* Kb = Kg + (size_t)b * NP_ * CI_;
    const unsigned short* Vb = Vt + (size_t)b * CI_ * NP_;

    f16x8 qf[2];
    #pragma unroll
    for (int u = 0; u < 2; ++u)
        qf[u] = *(const f16x8*)(Qg + ((size_t)b * HW_ + q0 + lr) * CI_ + u * 32 + lg * 8);

    f32x4 o_acc[4];
    #pragma unroll
    for (int dt = 0; dt < 4; ++dt) o_acc[dt] = (f32x4){0.f, 0.f, 0.f, 0.f};
    float mrun = -1e30f, lrun = 0.f;

#define STAGE(BUF, TT)                                                          \
    {                                                                           \
        const int kv0_ = (TT) * KVT_;                                           \
        if (wv == 0) {                                                          \
            _Pragma("unroll")                                                   \
            for (int i = 0; i < 4; ++i)                                         \
                gload_lds16(Kb + (size_t)(kv0_ + 8 * i + krow) * CI_ + kchk * 8,\
                            &Klds[BUF][i * 1024]);                              \
        } else {                                                                \
            _Pragma("unroll")                                                   \
            for (int i = 0; i < 4; ++i)                                         \
                gload_lds16(Vb + (size_t)(16 * i + vrow) * NP_ + kv0_ + vchk * 8,\
                            &Vlds[BUF][i * 1024]);                              \
        }                                                                       \
    }

#define COMPUTE(BUF)                                                            \
    {                                                                           \
        f16x8 kf[2][2];                                                         \
        _Pragma("unroll")                                                       \
        for (int u = 0; u < 2; ++u)                                             \
            _Pragma("unroll")                                                   \
            for (int k4 = 0; k4 < 2; ++k4)                                      \
                kf[u][k4] = *(const f16x8*)&Klds[BUF][(k4 * 16 + lr) * 128      \
                                + (((4 * u + lg) ^ (lr & 7)) << 4)];            \
        f32x4 s[2];                                                             \
        s[0] = (f32x4){0.f, 0.f, 0.f, 0.f};                                     \
        s[1] = (f32x4){0.f, 0.f, 0.f, 0.f};                                     \
        __builtin_amdgcn_s_setprio(1);                                          \
        _Pragma("unroll")                                                       \
        for (int u = 0; u < 2; ++u) {                                           \
            s[0] = mfma16h(kf[u][0], qf[u], s[0]);                              \
            s[1] = mfma16h(kf[u][1], qf[u], s[1]);                              \
        }                                                                       \
        __builtin_amdgcn_s_setprio(0);                                          \
        float tmax = fmaxf(fmaxf(fmaxf(s[0][0], s[0][1]),                       \
                                 fmaxf(s[0][2], s[0][3])),                      \
                           fmaxf(fmaxf(s[1][0], s[1][1]),                       \
                                 fmaxf(s[1][2], s[1][3])));                     \
        if (!__all(tmax <= mrun + 8.0f)) {                                      \
            tmax = fmaxf(tmax, __shfl_xor(tmax, 16));                           \
            tmax = fmaxf(tmax, __shfl_xor(tmax, 32));                           \
            const float mnew = fmaxf(mrun, tmax);                               \
            const float sc = __expf(mrun - mnew);                               \
            lrun *= sc;                                                         \
            _Pragma("unroll")                                                   \
            for (int r2 = 0; r2 < 4; ++r2) {                                    \
                const float scb = __shfl(sc, 4 * lg + r2);                      \
                _Pragma("unroll")                                               \
                for (int dt = 0; dt < 4; ++dt) o_acc[dt][r2] *= scb;            \
            }                                                                   \
            mrun = mnew;                                                        \
        }                                                                       \
        const float e00 = __expf(s[0][0] - mrun);                               \
        const float e01 = __expf(s[0][1] - mrun);                               \
        const float e02 = __expf(s[0][2] - mrun);                               \
        const float e03 = __expf(s[0][3] - mrun);                               \
        const float e10 = __expf(s[1][0] - mrun);                               \
        const float e11 = __expf(s[1][1] - mrun);                               \
        const float e12 = __expf(s[1][2] - mrun);                               \
        const float e13 = __expf(s[1][3] - mrun);                               \
        lrun += ((e00 + e01) + (e02 + e03)) + ((e10 + e11) + (e12 + e13));      \
        f16x8 pf = pk8(e00, e01, e02, e03, e10, e11, e12, e13);                 \
        __builtin_amdgcn_s_setprio(1);                                          \
        _Pragma("unroll")                                                       \
        for (int dt = 0; dt < 4; ++dt) {                                        \
            const int vrow_ = dt * 16 + lr;                                     \
            f16x8 vf = *(const f16x8*)&Vlds[BUF][vrow_ * 64                     \
                            + (((lg ^ (lr & 3))) << 4)];                        \
            o_acc[dt] = mfma16h(pf, vf, o_acc[dt]);                             \
        }                                                                       \
        __builtin_amdgcn_s_setprio(0);                                          \
    }

    STAGE(0, 0);
    STAGE(1, 1);

    for (int it = 0; it < NT_ / 2; ++it) {
        const int t0 = 2 * it;
        asm volatile("s_waitcnt vmcnt(4)" ::: "memory");
        __builtin_amdgcn_s_barrier();
        COMPUTE(0);
        __builtin_amdgcn_s_barrier();
        if (t0 + 2 < NT_) STAGE(0, t0 + 2);
        if (it == NT_ / 2 - 1) {
            asm volatile("s_waitcnt vmcnt(0)" ::: "memory");
        } else {
            asm volatile("s_waitcnt vmcnt(4)" ::: "memory");
        }
        __builtin_amdgcn_s_barrier();
        COMPUTE(1);
        __builtin_amdgcn_s_barrier();
        if (t0 + 3 < NT_) STAGE(1, t0 + 3);
    }

    // ---- Y finalize into LDS bounce (conv2 fragment layout) ----------------
    float lt = lrun;
    lt += __shfl_xor(lt, 16);
    lt += __shfl_xor(lt, 32);
    unsigned short* yb = (unsigned short*)&Klds[wv][0];   // [16][72] halves
    #pragma unroll
    for (int r2 = 0; r2 < 4; ++r2) {
        const float inv = 1.0f / __shfl(lt, 4 * lg + r2);
        #pragma unroll
        for (int dt = 0; dt < 4; ++dt)
            yb[(4 * lg + r2) * 72 + dt * 16 + lr] =
                __builtin_bit_cast(unsigned short, (_Float16)(o_acc[dt][r2] * inv));
    }

    // ---- fused conv-back: Z[o][q0+lr] = bW[o] + sum_ci wW[o][ci] Y[q0+lr][ci]
    float* wpart = (float*)&Vlds[0][0];                   // [2][32][2] floats
    f16x8 ya[2];
    #pragma unroll
    for (int u = 0; u < 2; ++u)
        ya[u] = *(const f16x8*)&yb[lr * 72 + u * 32 + lg * 8];

    unsigned short* Zb = Zh + (size_t)b * C_ * HW_ + q0 + lr;
    #pragma unroll
    for (int ot = 0; ot < 8; ++ot) {
        f32x4 D = (f32x4){0.f, 0.f, 0.f, 0.f};
        #pragma unroll
        for (int u = 0; u < 2; ++u) {
            f16x8 wa = *(const f16x8*)&wWh[(ot * 16 + lr) * CI_ + u * 32 + lg * 8];
            D = mfma16h(wa, ya[u], D);
        }
        float zs = 0.f, zq = 0.f;
        #pragma unroll
        for (int r2 = 0; r2 < 4; ++r2) {
            const int o = ot * 16 + 4 * lg + r2;
            const float z = D[r2] + bW[o];
            Zb[(size_t)o * HW_] = __builtin_bit_cast(unsigned short, (_Float16)z);
            zs += z;
            zq += z * z;
        }
        zs += __shfl_xor(zs, 1);  zq += __shfl_xor(zq, 1);
        zs += __shfl_xor(zs, 2);  zq += __shfl_xor(zq, 2);
        zs += __shfl_xor(zs, 4);  zq += __shfl_xor(zq, 4);
        zs += __shfl_xor(zs, 8);  zq += __shfl_xor(zq, 8);
        if (lr == 0) {
            wpart[(wv * 32 + ot * 4 + lg) * 2 + 0] = zs;
            wpart[(wv * 32 + ot * 4 + lg) * 2 + 1] = zq;
        }
    }
    __syncthreads();
    if (t < 64) {
        const int g = t >> 1, w = t & 1;
        const float v = wpart[(g) * 2 + w] + wpart[(32 + g) * 2 + w];
        gpart[(((size_t)b * NBLK_ + blockIdx.x) * 32 + g) * 2 + w] = v;
    }
#undef STAGE
#undef COMPUTE
}

// ---------------------------------------------------------------------------
// Kernel 5: fused GN stats-reduce + normalize + affine + residual (Z fp16).
// ---------------------------------------------------------------------------
__global__ __launch_bounds__(256) void final_kernel(
    const unsigned short* __restrict__ Zh, const float* __restrict__ xg,
    const float* __restrict__ gpart, const float* __restrict__ gnw,
    const float* __restrict__ gnb, float* __restrict__ out)
{
    __shared__ float red[256][2];
    const int t = threadIdx.x;
    const int c = blockIdx.x;
    const int b = blockIdx.y;
    const int zc = blockIdx.z;
    const int g = c >> 2;

    float v1 = 0.f, v2 = 0.f;
    for (int j = t; j < NBLK_; j += 256) {
        v1 += gpart[(((size_t)b * NBLK_ + j) * 32 + g) * 2 + 0];
        v2 += gpart[(((size_t)b * NBLK_ + j) * 32 + g) * 2 + 1];
    }
    red[t][0] = v1; red[t][1] = v2;
    __syncthreads();
    for (int off = 128; off > 0; off >>= 1) {
        if (t < off) { red[t][0] += red[t + off][0]; red[t][1] += red[t + off][1]; }
        __syncthreads();
    }
    const float invn = 1.0f / (4 * HW_);
    const float mean = red[0][0] * invn;
    const float var  = red[0][1] * invn - mean * mean;
    const float rstd = rsqrtf(var + EPS_);
    const float sc = rstd * gnw[c];
    const float sh = gnb[c] - mean * sc;

    const unsigned short* zp = Zh + ((size_t)b * C_ + c) * HW_;
    const float4* xp = (const float4*)(xg + ((size_t)b * C_ + c) * HW_);
    float4*       op = (float4*)(out + ((size_t)b * C_ + c) * HW_);
    #pragma unroll
    for (int i = 0; i < 3; ++i) {
        const int j = (zc * 3 + i) * 256 + t;
        const ushort4 zv = *(const ushort4*)(zp + (size_t)j * 4);
        const float4 xv = xp[j];
        float4 o;
        o.x = h2f(zv.x) * sc + sh + xv.x;
        o.y = h2f(zv.y) * sc + sh + xv.y;
        o.z = h2f(zv.z) * sc + sh + xv.z;
        o.w = h2f(zv.w) * sc + sh + xv.w;
        op[j] = o;
    }
}

// ---------------------------------------------------------------------------
extern "C" void kernel_launch(void* const* d_in, const int* in_sizes, int n_in,
                              void* d_out, int out_size, void* d_ws, size_t ws_size,
                              hipStream_t stream)
{
    const float* x       = (const float*)d_in[0];
    const float* w_theta = (const float*)d_in[1];
    const float* b_theta = (const float*)d_in[2];
    const float* w_phi   = (const float*)d_in[3];
    const float* b_phi   = (const float*)d_in[4];
    const float* w_g     = (const float*)d_in[5];
    const float* b_g     = (const float*)d_in[6];
    const float* w_W     = (const float*)d_in[7];
    const float* b_W     = (const float*)d_in[8];
    const float* gn_w    = (const float*)d_in[9];
    const float* gn_b    = (const float*)d_in[10];
    float* out = (float*)d_out;
    char* wsb  = (char*)d_ws;

    // workspace layout (bytes)
    unsigned short* Q    = (unsigned short*)(wsb);             //  4,718,592
    unsigned short* K    = (unsigned short*)(wsb +  4718592);  //  1,179,648
    unsigned short* Vt   = (unsigned short*)(wsb +  5898240);  //  1,179,648
    float* gpart         = (float*)(wsb + 11796480);           //    294,912
    unsigned short* Zh   = (unsigned short*)(wsb + 16515072);  //  9,437,184 (fp16)
    unsigned short* Whall= (unsigned short*)(wsb + 35390464);  //     65,536
    const unsigned short* wWh = Whall + 24576;

    wprep_kernel<<<128, 256, 0, stream>>>(w_theta, w_phi, w_g, w_W, Whall);
    proj_kernel <<<dim3(288, B_), 128, 0, stream>>>(
        x, Whall, b_theta, b_phi, b_g, Q, K, Vt);
    attn_kernel <<<dim3(HW_ / 32, B_), 128, 0, stream>>>(
        Q, K, Vt, wWh, b_W, Zh, gpart);
    final_kernel<<<dim3(C_, B_, 3), 256, 0, stream>>>(Zh, x, gpart, gn_w, gn_b, out);
}